// Round 3
// baseline (409.097 us; speedup 1.0000x reference)
//
#include <hip/hip_runtime.h>

// A=500 atoms, R=14 reps, n_ao=5800, out=[A,A,R,R]=49M f32 (196 MB).
// out[a1,a2,r1,r2] = feat[inv(a1,r1), inv(a2,r2)] or 0 at empty slots,
// inv(a,r) = arow[a] + pm[a*R+r] (pm<0 = empty). Collision-free.
//
// v4 "wave-private pipeline": zero barriers in the hot loop. Each wave owns a
// private 14x80 LDS window and processes 25 tiles as 5 groups of 5 a2-atoms:
//   issue coalesced float4 loads of group g+1 -> regs   (flies under emit)
//   emit group g: 980 contiguous floats, float4 stores  (LDS-permuted reads)
//   ds_write regs -> private buf (DS in-order per wave => no sync needed)
// All permutation indices are per-lane constants hoisted out of the loop;
// s_cof is precomputed group-relative so inner loop = add + 2 LDS reads + sel.
constexpr int R = 14;
constexpr int A = 500;
constexpr int TOTAL = A * R;       // 7000
constexpr int TILE = R * R;        // 196
constexpr int APB = 100;           // a2 atoms per block
constexpr int BPA = A / APB;       // 5 blocks per a1
constexpr int GA = 5;              // a2 atoms per wave-group
constexpr int TPW = 25;            // tiles per wave (4 waves * 25 = APB)
constexpr int NGRP = TPW / GA;     // 5 groups per wave
constexpr int WPW = 80;            // LDS row stride (floats); window <= 76
constexpr int SLOT4 = WPW / 4;     // 20 float4 slots per row
constexpr int BUFSZ = R * WPW;     // 1120 floats per wave buffer
constexpr int GPB = 4 * NGRP;      // 20 groups per block
constexpr int SENT = (int)0xC0000000;  // -(1<<30)

// ---- fused setup: one block (unchanged, known-good) ----------------------
__global__ __launch_bounds__(1024) void setup_kernel(
        const int* __restrict__ dst, int n_ao,
        int* __restrict__ inv, int* __restrict__ arow,
        int* __restrict__ ncols, int* __restrict__ pm) {
    int tid = threadIdx.x;
    for (int t = tid; t < TOTAL; t += 1024) inv[t] = -1;
    __syncthreads();
    for (int t = tid; t < n_ao; t += 1024) inv[dst[t]] = t;  // collision-free
    __syncthreads();
    if (tid < A) {
        int a = tid, lo = 0x7fffffff, hi = -1;
#pragma unroll
        for (int r = 0; r < R; ++r) {
            int v = inv[a * R + r];
            if (v >= 0) { lo = min(lo, v); hi = max(hi, v); }
        }
        arow[a] = lo;
        ncols[a] = hi - lo + 1;
#pragma unroll
        for (int r = 0; r < R; ++r) {
            int v = inv[a * R + r];
            pm[a * R + r] = (v >= 0) ? (v - lo) : -1;
        }
    }
}

// ---- main: 2500 blocks x 256 threads; wave = (a1, 25 a2 tiles) -----------
__global__ __launch_bounds__(256, 6) void wave_kernel(
        const float* __restrict__ feat,
        const int* __restrict__ arow,
        const int* __restrict__ ncols,
        const int* __restrict__ pm,
        float* __restrict__ out, int n_ao) {
    const int a1     = blockIdx.x / BPA;
    const int a2base = (blockIdx.x % BPA) * APB;
    const int tid    = threadIdx.x;
    const int wave   = tid >> 6;
    const int lane   = tid & 63;

    __shared__ float buf[4][BUFSZ];      // wave-private windows (17.9 KB)
    __shared__ int s_cof[APB * R];       // group-relative col offsets / SENT
    __shared__ int s_gA[GPB];            // aligned window start col per group
    __shared__ int s_gW[GPB];            // float4 width per group

    // ---- block setup (once) ----
    if (tid < GPB) {
        const int g0 = a2base + tid * GA;
        const int colA = arow[g0] & ~3;                   // 16B align
        s_gA[tid] = colA;
        s_gW[tid] = (arow[g0 + GA - 1] + ncols[g0 + GA - 1] - colA + 3) >> 2;
    }
    for (int t = tid; t < APB * R; t += 256) {
        const int i   = t / R;                            // a2 within block
        const int a2  = a2base + i;
        const int pmv = pm[a2base * R + t];               // coalesced
        const int colA = arow[a2base + (i / GA) * GA] & ~3;
        s_cof[t] = (pmv >= 0) ? (arow[a2] + pmv - colA) : SENT;
    }

    // ---- per-lane constants (whole kernel) ----
    const int arow1 = arow[a1];
    const int n1    = ncols[a1];
    const int rs4   = n_ao >> 2;
    const float4* featR =
        reinterpret_cast<const float4*>(feat) + (long long)arow1 * rs4;

    int row_[5], slot_[5];                // stage mapping (row, float4 slot)
#pragma unroll
    for (int p = 0; p < 5; ++p) {
        const int q = p * 64 + lane;
        row_[p]  = q / SLOT4;
        slot_[p] = q - row_[p] * SLOT4;
    }

    int rb_[4][4], toff_[4][4];           // emit: LDS row base, cof offset
    bool act_[4];
#pragma unroll
    for (int p = 0; p < 4; ++p) {
        const int o4 = p * 64 + lane;
        act_[p] = (o4 < (GA * TILE) / 4); // o4 < 245
        int e4 = (act_[p] ? o4 : 0) * 4;
        int t  = e4 / TILE;
        int e  = e4 - t * TILE;
        int r1 = e / R;
        int r2 = e - r1 * R;
#pragma unroll
        for (int k = 0; k < 4; ++k) {
            const int dd = pm[a1 * R + r1];
            rb_[p][k]   = (dd >= 0) ? dd * WPW : SENT;
            toff_[p][k] = t * R + r2;
            if (++r2 == R) { r2 = 0; ++r1; }
        }
    }
    __syncthreads();                      // the only barrier

    const int i0   = wave * TPW;          // first tile (within block)
    const int gidb = wave * NGRP;         // first group (within block tables)
    float* outg = out + ((long long)(a1 * A + a2base + i0)) * TILE;
    float* const bufw = &buf[wave][0];

    float4 rg[5];                         // in-flight stage registers

    auto issue_loads = [&](int grp) {
        const int cA4 = s_gA[gidb + grp] >> 2;
        const int W4  = s_gW[gidb + grp];
#pragma unroll
        for (int p = 0; p < 5; ++p)
            if (row_[p] < n1 && slot_[p] < W4)
                rg[p] = featR[(long long)row_[p] * rs4 + cA4 + slot_[p]];
    };
    auto write_lds = [&](int grp) {
        const int W4 = s_gW[gidb + grp];
#pragma unroll
        for (int p = 0; p < 5; ++p)
            if (row_[p] < n1 && slot_[p] < W4)
                *reinterpret_cast<float4*>(&bufw[row_[p] * WPW + slot_[p] * 4]) = rg[p];
    };
    auto emit = [&](int grp) {
        const int cb = (i0 + grp * GA) * R;       // base into s_cof
        float* og = outg + grp * (GA * TILE);
#pragma unroll
        for (int p = 0; p < 4; ++p) {
            if (act_[p]) {
                float4 v;
                float* vp = &v.x;
#pragma unroll
                for (int k = 0; k < 4; ++k) {
                    const int cof = s_cof[cb + toff_[p][k]];
                    const int idx = rb_[p][k] + cof;     // <0 iff any empty
                    const float x = bufw[max(idx, 0)];
                    vp[k] = (idx >= 0) ? x : 0.0f;
                }
                *reinterpret_cast<float4*>(og + (p * 64 + lane) * 4) = v;
            }
        }
    };

    // ---- barrier-free pipelined loop ----
    issue_loads(0);
    write_lds(0);                         // waits vmcnt (prologue only)
    for (int g = 0; g < NGRP; ++g) {
        if (g + 1 < NGRP) issue_loads(g + 1);   // HBM flies under emit
        emit(g);                                 // reads buf, stores out
        if (g + 1 < NGRP) write_lds(g + 1);      // DS in-order after reads
    }
}

extern "C" void kernel_launch(void* const* d_in, const int* in_sizes, int n_in,
                              void* d_out, int out_size, void* d_ws, size_t ws_size,
                              hipStream_t stream) {
    const float* feat = (const float*)d_in[0];
    const int*   dst  = (const int*)d_in[1];
    int n_ao = in_sizes[1];              // 5800

    int* inv   = (int*)d_ws;             // 7000
    int* arow  = inv + TOTAL;            // 500
    int* ncols = arow + A;               // 500
    int* pm    = ncols + A;              // 7000

    setup_kernel<<<1, 1024, 0, stream>>>(dst, n_ao, inv, arow, ncols, pm);
    wave_kernel<<<A * BPA, 256, 0, stream>>>(feat, arow, ncols, pm,
                                             (float*)d_out, n_ao);
}

// Round 5
// 302.155 us; speedup vs baseline: 1.3539x; 1.3539x over previous
//
#include <hip/hip_runtime.h>

// A=500 atoms, R=14 reps, n_ao=5800, out=[A,A,R,R]=49M f32 (196 MB).
// out[a1,a2,r1,r2] = feat[inv(a1,r1), inv(a2,r2)] or 0 at empty slots,
// inv(a,r) = arow[a] + pm[a*R+r] (pm<0 = empty). Collision-free.
//
// v6 = v5 with the correctness fix: s_pc staged SENT-coded (-2^30) so the
// single sign test idx = rb + off + c < 0 catches EMPTY COLUMN slots too
// (v5 left them as -1, which only offset the index by one -> garbage reads).
//   - per-lane emit decode hoisted out of the super loop (super-invariant)
//   - all per-super tables staged once up front
//   - stage loop fixed-trip unrolled -> 4 global loads in flight
//   - nontemporal float4 loads/stores (each byte touched exactly once)
//   - WP 364 (%32=12 -> 8-row LDS bank period on emit reads)
constexpr int R = 14;
constexpr int A = 500;
constexpr int TOTAL = A * R;          // 7000
constexpr int TILE = R * R;           // 196
constexpr int G = 25;                 // a2 atoms per super
constexpr int NG = A / G;             // 20
constexpr int SUPER = 4;              // supers per block
constexpr int NSUP = NG / SUPER;      // 5
constexpr int WP = 364;               // LDS row stride; %32=12 -> 8-row period
constexpr int CHUNK = G * TILE;       // 4900 floats per super
constexpr int SENT = (int)0xC0000000; // -(1<<30)

typedef float v4f __attribute__((ext_vector_type(4)));

// ---- fused setup: one block (unchanged, known-good) ----------------------
__global__ __launch_bounds__(1024) void setup_kernel(
        const int* __restrict__ dst, int n_ao,
        int* __restrict__ inv, int* __restrict__ arow,
        int* __restrict__ ncols, int* __restrict__ pm) {
    int tid = threadIdx.x;
    for (int t = tid; t < TOTAL; t += 1024) inv[t] = -1;
    __syncthreads();
    for (int t = tid; t < n_ao; t += 1024) inv[dst[t]] = t;  // collision-free
    __syncthreads();
    if (tid < A) {
        int a = tid, lo = 0x7fffffff, hi = -1;
#pragma unroll
        for (int r = 0; r < R; ++r) {
            int v = inv[a * R + r];
            if (v >= 0) { lo = min(lo, v); hi = max(hi, v); }
        }
        arow[a] = lo;
        ncols[a] = hi - lo + 1;
#pragma unroll
        for (int r = 0; r < R; ++r) {
            int v = inv[a * R + r];
            pm[a * R + r] = (v >= 0) ? (v - lo) : -1;
        }
    }
}

// ---- main: 2500 blocks x 512 threads; block = (a1, 4 supers of 25 a2) ----
__global__ __launch_bounds__(512, 8) void tile_kernel(
        const float* __restrict__ feat,
        const int* __restrict__ arow,
        const int* __restrict__ ncols,
        const int* __restrict__ pm,
        float* __restrict__ out, int n_ao) {
    const int gs  = blockIdx.x % NSUP;
    const int a1  = blockIdx.x / NSUP;
    const int tid = threadIdx.x;

    __shared__ float buf[R * WP];         // 20.4 KB staging window
    __shared__ int s_pc[SUPER][G * R];    // SENT-coded pm for the 100 atoms
    __shared__ int s_off[SUPER][G];       // arow[a2] - colA per super

    const int arow1 = arow[a1];
    const int n1    = ncols[a1];
    const int gbase = gs * (SUPER * G);   // first a2 atom of this block

    // ---- all tables once, up front (published by stage(0)'s barrier) ----
    for (int t = tid; t < SUPER * G * R; t += 512) {
        const int pmv = pm[gbase * R + t];                // contiguous copy
        (&s_pc[0][0])[t] = (pmv >= 0) ? pmv : SENT;       // FIX: SENT-code
    }
    if (tid < SUPER * G) {
        const int sI = tid / G, i = tid - sI * G;
        const int g0 = gbase + sI * G;
        s_off[sI][i] = arow[g0 + i] - (arow[g0] & ~3);
    }

    // ---- per-lane emit decode, computed ONCE (super-invariant) ----
    // reads pm from global (L1/L2-cached) so no LDS dependency here
    int rb_[3][4], ci_[3][4], a2i_[3];
    bool val_[3];
#pragma unroll
    for (int j = 0; j < 3; ++j) {
        const int o4 = tid * 4 + j * 2048;
        val_[j] = (o4 < CHUNK);
        const int o = val_[j] ? o4 : 0;
        int a2i = o / TILE;               // magic mul (float4 stays in tile)
        int e   = o - a2i * TILE;
        int r1  = e / R;                  // magic mul
        int r2  = e - r1 * R;
        a2i_[j] = a2i;
#pragma unroll
        for (int k = 0; k < 4; ++k) {
            const int dd = pm[a1 * R + r1];
            rb_[j][k] = (dd >= 0) ? dd * WP : SENT;       // LDS row base
            ci_[j][k] = a2i * R + r2;                     // index into s_pc[s]
            if (++r2 == R) { r2 = 0; ++r1; }
        }
    }

    const int d0  = tid >> 7;             // 0..3: row phase
    const int c4  = tid & 127;            // float4 column slot
    const int rs4 = n_ao >> 2;

    auto stage = [&](int s) {
        const int g0   = gbase + s * G;
        const int colA = arow[g0] & ~3;                   // 16B align (uniform)
        const int W4   = (arow[g0 + G - 1] + ncols[g0 + G - 1] - colA + 3) >> 2;
        if (c4 < W4) {
            const v4f* src = reinterpret_cast<const v4f*>(feat)
                           + (long long)arow1 * rs4 + (colA >> 2) + c4;
#pragma unroll
            for (int u = 0; u < 4; ++u) {                 // 4 loads in flight
                const int d = d0 + u * 4;
                if (d < n1)
                    *reinterpret_cast<v4f*>(&buf[d * WP + (c4 << 2)]) =
                        __builtin_nontemporal_load(src + (long long)d * rs4);
            }
        }
    };

    auto emit = [&](int s) {
        const long long outbase =
            ((long long)a1 * A + gbase + s * G) * (long long)TILE;
        const int* pcS = &s_pc[s][0];
#pragma unroll
        for (int j = 0; j < 3; ++j) {
            if (!val_[j]) continue;       // only j=2 partial (tid<201)
            const int off = s_off[s][a2i_[j]];
            v4f v;
#pragma unroll
            for (int k = 0; k < 4; ++k) {
                const int c   = pcS[ci_[j][k]];           // pm or SENT
                const int idx = rb_[j][k] + off + c;      // <0 iff any empty
                const float x = buf[max(idx, 0)];
                ((float*)&v)[k] = (idx >= 0) ? x : 0.0f;
            }
            __builtin_nontemporal_store(
                v, reinterpret_cast<v4f*>(out + outbase + tid * 4 + j * 2048));
        }
    };

    // ---- v0's proven schedule: stage -> sync -> emit -> sync -------------
    stage(0);
    __syncthreads();                      // also publishes the tables
    for (int s = 0; s < SUPER; ++s) {
        emit(s);
        if (s + 1 < SUPER) {
            __syncthreads();
            stage(s + 1);
            __syncthreads();
        }
    }
}

extern "C" void kernel_launch(void* const* d_in, const int* in_sizes, int n_in,
                              void* d_out, int out_size, void* d_ws, size_t ws_size,
                              hipStream_t stream) {
    const float* feat = (const float*)d_in[0];
    const int*   dst  = (const int*)d_in[1];
    int n_ao = in_sizes[1];              // 5800

    int* inv   = (int*)d_ws;             // 7000
    int* arow  = inv + TOTAL;            // 500
    int* ncols = arow + A;               // 500
    int* pm    = ncols + A;              // 7000

    setup_kernel<<<1, 1024, 0, stream>>>(dst, n_ao, inv, arow, ncols, pm);
    tile_kernel<<<A * NSUP, 512, 0, stream>>>(feat, arow, ncols, pm,
                                              (float*)d_out, n_ao);
}

// Round 6
// 300.244 us; speedup vs baseline: 1.3625x; 1.0064x over previous
//
#include <hip/hip_runtime.h>

// A=500 atoms, R=14 reps, n_ao=5800, out=[A,A,R,R]=49M f32 (196 MB).
// out[a1,a2,r1,r2] = feat[inv(a1,r1), inv(a2,r2)] or 0 at empty slots,
// inv(a,r) = arow[a] + pm[a*R+r] (pm<0 = empty). Collision-free.
//
// v7 = v6 + (a) T14 reg-prefetch: super s+1's global loads issued BEFORE
// emit(s), so HBM latency hides under the emit phase; after the barrier only
// ds_write + barrier remain. Single LDS buffer, same 2 barriers/super, same
// 26 KB LDS -> keeps 4 blocks/CU (v2's double-buffer occupancy loss avoided).
// (b) s_off folded into the column table at staging time:
// s_cof = arow[a2]-colA+pm (SENT-coded) -> emit inner step = one LDS read+add.
constexpr int R = 14;
constexpr int A = 500;
constexpr int TOTAL = A * R;          // 7000
constexpr int TILE = R * R;           // 196
constexpr int G = 25;                 // a2 atoms per super
constexpr int NG = A / G;             // 20
constexpr int SUPER = 4;              // supers per block
constexpr int NSUP = NG / SUPER;      // 5
constexpr int WP = 364;               // LDS row stride; %32=12 -> 8-row period
constexpr int CHUNK = G * TILE;       // 4900 floats per super
constexpr int SENT = (int)0xC0000000; // -(1<<30)

typedef float v4f __attribute__((ext_vector_type(4)));

// ---- fused setup: one block (unchanged, known-good) ----------------------
__global__ __launch_bounds__(1024) void setup_kernel(
        const int* __restrict__ dst, int n_ao,
        int* __restrict__ inv, int* __restrict__ arow,
        int* __restrict__ ncols, int* __restrict__ pm) {
    int tid = threadIdx.x;
    for (int t = tid; t < TOTAL; t += 1024) inv[t] = -1;
    __syncthreads();
    for (int t = tid; t < n_ao; t += 1024) inv[dst[t]] = t;  // collision-free
    __syncthreads();
    if (tid < A) {
        int a = tid, lo = 0x7fffffff, hi = -1;
#pragma unroll
        for (int r = 0; r < R; ++r) {
            int v = inv[a * R + r];
            if (v >= 0) { lo = min(lo, v); hi = max(hi, v); }
        }
        arow[a] = lo;
        ncols[a] = hi - lo + 1;
#pragma unroll
        for (int r = 0; r < R; ++r) {
            int v = inv[a * R + r];
            pm[a * R + r] = (v >= 0) ? (v - lo) : -1;
        }
    }
}

// ---- main: 2500 blocks x 512 threads; block = (a1, 4 supers of 25 a2) ----
__global__ __launch_bounds__(512, 8) void tile_kernel(
        const float* __restrict__ feat,
        const int* __restrict__ arow,
        const int* __restrict__ ncols,
        const int* __restrict__ pm,
        float* __restrict__ out, int n_ao) {
    const int gs  = blockIdx.x % NSUP;
    const int a1  = blockIdx.x / NSUP;
    const int tid = threadIdx.x;

    __shared__ float buf[R * WP];         // 20.4 KB staging window
    __shared__ int s_cof[SUPER * G * R];  // arow[a2]-colA+pm, SENT-coded

    const int arow1 = arow[a1];
    const int n1    = ncols[a1];
    const int gbase = gs * (SUPER * G);   // first a2 atom of this block

    // ---- column table once, up front (published by first barrier) ----
    for (int t = tid; t < SUPER * G * R; t += 512) {
        const int i    = t / R;                           // a2 within block
        const int a2   = gbase + i;
        const int colA = arow[gbase + (i / G) * G] & ~3;  // super's align base
        const int pmv  = pm[gbase * R + t];               // contiguous copy
        s_cof[t] = (pmv >= 0) ? (arow[a2] - colA + pmv) : SENT;
    }

    // ---- per-lane emit decode, computed ONCE (super-invariant) ----
    int rb_[3][4], ci_[3][4];
    bool val_[3];
#pragma unroll
    for (int j = 0; j < 3; ++j) {
        const int o4 = tid * 4 + j * 2048;
        val_[j] = (o4 < CHUNK);
        const int o = val_[j] ? o4 : 0;
        int a2i = o / TILE;               // magic mul (float4 stays in tile)
        int e   = o - a2i * TILE;
        int r1  = e / R;                  // magic mul
        int r2  = e - r1 * R;
#pragma unroll
        for (int k = 0; k < 4; ++k) {
            const int dd = pm[a1 * R + r1];
            rb_[j][k] = (dd >= 0) ? dd * WP : SENT;       // LDS row base
            ci_[j][k] = a2i * R + r2;                     // index into s_cof[s]
            if (++r2 == R) { r2 = 0; ++r1; }
        }
    }

    const int d0  = tid >> 7;             // 0..3: row phase
    const int c4  = tid & 127;            // float4 column slot
    const int rs4 = n_ao >> 2;

    v4f rg[4];                            // in-flight prefetch registers

    auto issue_loads = [&](int s) {       // global -> rg (no waits)
        const int g0   = gbase + s * G;
        const int colA = arow[g0] & ~3;
        const int W4   = (arow[g0 + G - 1] + ncols[g0 + G - 1] - colA + 3) >> 2;
        if (c4 < W4) {
            const v4f* src = reinterpret_cast<const v4f*>(feat)
                           + (long long)arow1 * rs4 + (colA >> 2) + c4;
#pragma unroll
            for (int u = 0; u < 4; ++u) {
                const int d = d0 + u * 4;
                if (d < n1)
                    rg[u] = __builtin_nontemporal_load(src + (long long)d * rs4);
            }
        }
    };
    auto write_lds = [&](int s) {         // rg -> buf
        const int g0   = gbase + s * G;
        const int colA = arow[g0] & ~3;
        const int W4   = (arow[g0 + G - 1] + ncols[g0 + G - 1] - colA + 3) >> 2;
        if (c4 < W4) {
#pragma unroll
            for (int u = 0; u < 4; ++u) {
                const int d = d0 + u * 4;
                if (d < n1)
                    *reinterpret_cast<v4f*>(&buf[d * WP + (c4 << 2)]) = rg[u];
            }
        }
    };

    auto emit = [&](int s) {
        const long long outbase =
            ((long long)a1 * A + gbase + s * G) * (long long)TILE;
        const int* pcS = &s_cof[s * G * R];
#pragma unroll
        for (int j = 0; j < 3; ++j) {
            if (!val_[j]) continue;       // only j=2 partial (tid<201)
            v4f v;
#pragma unroll
            for (int k = 0; k < 4; ++k) {
                const int cof = pcS[ci_[j][k]];           // col offset or SENT
                const int idx = rb_[j][k] + cof;          // <0 iff any empty
                const float x = buf[max(idx, 0)];
                ((float*)&v)[k] = (idx >= 0) ? x : 0.0f;
            }
            __builtin_nontemporal_store(
                v, reinterpret_cast<v4f*>(out + outbase + tid * 4 + j * 2048));
        }
    };

    // ---- schedule: prefetch s+1 under emit(s); single buffer, 2 barriers --
    issue_loads(0);
    write_lds(0);                         // vmcnt wait here (prologue only)
    __syncthreads();                      // also publishes s_cof
    for (int s = 0; s < SUPER; ++s) {
        if (s + 1 < SUPER) issue_loads(s + 1);  // HBM latency hides under emit
        emit(s);
        if (s + 1 < SUPER) {
            __syncthreads();              // all emit(s) reads done
            write_lds(s + 1);             // loads already landed
            __syncthreads();              // ds_writes visible
        }
    }
}

extern "C" void kernel_launch(void* const* d_in, const int* in_sizes, int n_in,
                              void* d_out, int out_size, void* d_ws, size_t ws_size,
                              hipStream_t stream) {
    const float* feat = (const float*)d_in[0];
    const int*   dst  = (const int*)d_in[1];
    int n_ao = in_sizes[1];              // 5800

    int* inv   = (int*)d_ws;             // 7000
    int* arow  = inv + TOTAL;            // 500
    int* ncols = arow + A;               // 500
    int* pm    = ncols + A;              // 7000

    setup_kernel<<<1, 1024, 0, stream>>>(dst, n_ao, inv, arow, ncols, pm);
    tile_kernel<<<A * NSUP, 512, 0, stream>>>(feat, arow, ncols, pm,
                                              (float*)d_out, n_ao);
}